// Round 12
// baseline (181.207 us; speedup 1.0000x reference)
//
#include <hip/hip_runtime.h>
#include <hip/hip_bf16.h>

static constexpr float SLOPE = 0.01f;   // leaky_relu negative_slope
static constexpr float EPSN  = 1e-12f;  // F.normalize eps

typedef float f32x4 __attribute__((ext_vector_type(4)));
typedef short short8 __attribute__((ext_vector_type(8)));

#define KPAD 512     // in_dim = 500 padded to 16 k-steps of 32 (8 tiles of 64)
#define CAP  16      // edges per node cached in LDS for routing iters 2,3

// VALU (DPP) butterfly/rotate add: x + dpp(x). No DS-pipe traffic.
// 0xB1 = quad_perm[1,0,3,2] (xor1); 0x4E = quad_perm[2,3,0,1] (xor2);
// 0x141 = row_half_mirror (xor7 within 8-lane group); 0x128 = row_ror:8 (xor8 in 16-row).
template <int CTRL>
__device__ __forceinline__ float dpp_add(float x) {
  const int y = __builtin_amdgcn_mov_dpp(__builtin_bit_cast(int, x), CTRL, 0xF, 0xF, true);
  return x + __builtin_bit_cast(float, y);
}

// round-to-nearest bf16 split: v ~= hi + lo, each exactly representable in bf16
__device__ __forceinline__ void bf16_split(float v, short& hi, short& lo) {
  __hip_bfloat16 h = __float2bfloat16(v);
  float hf = __bfloat162float(h);
  __hip_bfloat16 l = __float2bfloat16(v - hf);
  hi = __builtin_bit_cast(short, h);
  lo = __builtin_bit_cast(short, l);
}

// async global->LDS DMA, 16B per lane. LDS dest = base + lane*16 (linear).
__device__ __forceinline__ void load_lds16(const float* g, float* l) {
  __builtin_amdgcn_global_load_lds(
      (const __attribute__((address_space(1))) unsigned int*)g,
      (__attribute__((address_space(3))) unsigned int*)l, 16, 0, 0);
}

// ---------------------------------------------------------------------------
// One-time W prep: split to bf16 hi/lo, swizzle to w2[kstep][kc][col][8],
// zero-pad k to KPAD. Also zeroes the 16B zbuf used for A-tail redirect.
// ---------------------------------------------------------------------------
__global__ __launch_bounds__(256) void prep_w_k(const float* __restrict__ W,
                                                short* __restrict__ w2h,
                                                short* __restrict__ w2l,
                                                float* __restrict__ zbuf, int in_dim) {
  const int idx = blockIdx.x * 256 + threadIdx.x;   // over KPAD*64
  if (idx < 4) zbuf[idx] = 0.0f;
  if (idx >= KPAD * 64) return;
  const int k = idx >> 6, col = idx & 63;
  const float v = (k < in_dim) ? W[(size_t)k * 64 + col] : 0.0f;
  short hi, lo;
  bf16_split(v, hi, lo);
  const int kt = k >> 5, kc = (k >> 3) & 3, e = k & 7;
  const int off = (((kt * 4 + kc) * 64) + col) * 8 + e;
  w2h[off] = hi;
  w2l[off] = lo;
}

// ---------------------------------------------------------------------------
// Stage one 16-row x 64-float A tile via 4 async DMA calls (r9 structure).
// ---------------------------------------------------------------------------
__device__ __forceinline__ void stage_tile(const float* __restrict__ x,
                                           const float* __restrict__ zbuf,
                                           float* ldsbuf, int row0w, int kt,
                                           int n, int in_dim, int lane) {
  const int rl = lane >> 4;          // row within 4-row call group
  const int gl = lane & 15;          // destination granule slot
#pragma unroll
  for (int i = 0; i < 4; ++i) {
    const int r    = i * 4 + rl;
    const int gsrc = gl ^ (r & 7);
    const int k    = kt * 64 + gsrc * 4;
    int grow = row0w + r;
    grow = grow < n ? grow : n - 1;
    const float* src = (k + 4 <= in_dim) ? (x + (size_t)grow * in_dim + k) : zbuf;
    load_lds16(src, ldsbuf + i * 256);   // 4 rows * 64 floats per call
  }
}

// ---------------------------------------------------------------------------
// Fused MFMA GEMM (r9 structure, measured 66us): xn = capsnorm(lrelu(x@W+b)).
// Per-wave-private double-buffered A tiles staged with global_load_lds.
// ---------------------------------------------------------------------------
__global__ __launch_bounds__(256) void gemm_mfma_capsnorm_k(
    const float* __restrict__ x, const short* __restrict__ w2h,
    const short* __restrict__ w2l, const float* __restrict__ b,
    const float* __restrict__ zbuf, float* __restrict__ xn, int n, int in_dim) {
  __shared__ __align__(16) float xs[4][2][1024];   // [wave][buf][16 rows x 64 f]

  const int tid   = threadIdx.x;
  const int lane  = tid & 63;
  const int w     = tid >> 6;
  const int l15   = lane & 15;
  const int kcL   = lane >> 4;
  const int row0  = blockIdx.x * 64;
  const int row0w = row0 + w * 16;
  const int sw4   = l15 & 7;

  f32x4 acc0 = {0.f, 0.f, 0.f, 0.f};
  f32x4 acc1 = {0.f, 0.f, 0.f, 0.f};
  f32x4 acc2 = {0.f, 0.f, 0.f, 0.f};
  f32x4 acc3 = {0.f, 0.f, 0.f, 0.f};

  stage_tile(x, zbuf, &xs[w][0][0], row0w, 0, n, in_dim, lane);

  for (int kt = 0; kt < 8; ++kt) {
    float* cur = &xs[w][kt & 1][0];
    float* nxt = &xs[w][(kt & 1) ^ 1][0];

    const int s00 = ((kcL * 2)     ^ sw4) * 4;
    const int s01 = ((kcL * 2 + 1) ^ sw4) * 4;
    const int s10 = ((8 + kcL * 2)     ^ sw4) * 4;
    const int s11 = ((8 + kcL * 2 + 1) ^ sw4) * 4;
    const float4 fa0 = *reinterpret_cast<const float4*>(&cur[l15 * 64 + s00]);
    const float4 fb0 = *reinterpret_cast<const float4*>(&cur[l15 * 64 + s01]);
    const float4 fa1 = *reinterpret_cast<const float4*>(&cur[l15 * 64 + s10]);
    const float4 fb1 = *reinterpret_cast<const float4*>(&cur[l15 * 64 + s11]);

    if (kt < 7) stage_tile(x, zbuf, nxt, row0w, kt + 1, n, in_dim, lane);

#pragma unroll
    for (int ks = 0; ks < 2; ++ks) {
      const float4 A0 = ks ? fa1 : fa0;
      const float4 A1 = ks ? fb1 : fb0;
      short hb[8], lb[8];
      bf16_split(A0.x, hb[0], lb[0]);
      bf16_split(A0.y, hb[1], lb[1]);
      bf16_split(A0.z, hb[2], lb[2]);
      bf16_split(A0.w, hb[3], lb[3]);
      bf16_split(A1.x, hb[4], lb[4]);
      bf16_split(A1.y, hb[5], lb[5]);
      bf16_split(A1.z, hb[6], lb[6]);
      bf16_split(A1.w, hb[7], lb[7]);
      const short8 ah = *reinterpret_cast<const short8*>(hb);
      const short8 al = *reinterpret_cast<const short8*>(lb);
      const int ktg = kt * 2 + ks;
      const size_t base = ((size_t)(ktg * 4 + kcL) * 64) * 8;
#pragma unroll
      for (int nt = 0; nt < 4; ++nt) {
        const short8 bh = *reinterpret_cast<const short8*>(w2h + base + (size_t)(nt * 16 + l15) * 8);
        const short8 bl = *reinterpret_cast<const short8*>(w2l + base + (size_t)(nt * 16 + l15) * 8);
        f32x4& acc = nt == 0 ? acc0 : nt == 1 ? acc1 : nt == 2 ? acc2 : acc3;
        acc = __builtin_amdgcn_mfma_f32_16x16x32_bf16(ah, bh, acc, 0, 0, 0);
        acc = __builtin_amdgcn_mfma_f32_16x16x32_bf16(ah, bl, acc, 0, 0, 0);
        acc = __builtin_amdgcn_mfma_f32_16x16x32_bf16(al, bh, acc, 0, 0, 0);
      }
    }
  }

  // --- epilogue: bias + leaky_relu + capsnorm ---
#pragma unroll
  for (int nt = 0; nt < 4; ++nt) {
    const f32x4 acc = nt == 0 ? acc0 : nt == 1 ? acc1 : nt == 2 ? acc2 : acc3;
    const float bcol = b[nt * 16 + l15];
#pragma unroll
    for (int reg = 0; reg < 4; ++reg) {
      float v = acc[reg] + bcol;
      v = v > 0.f ? v : SLOPE * v;
      float s = v * v;
      s = dpp_add<0xB1>(s);        // xor1 (VALU)
      s = dpp_add<0x4E>(s);        // xor2 (VALU)
      s += __shfl_xor(s, 4);       // xor4
      const float inv = 1.0f / fmaxf(sqrtf(s), EPSN);
      const int grow = row0 + w * 16 + ((lane >> 4) << 2) + reg;
      if (grow < n) xn[(size_t)grow * 64 + nt * 16 + l15] = v * inv;
    }
  }
}

// ---------------------------------------------------------------------------
// CSR construction: counts -> exclusive scan -> cursor scatter
// ---------------------------------------------------------------------------
__global__ __launch_bounds__(256) void zero_int_k(int* __restrict__ p, int n) {
  const int i = blockIdx.x * blockDim.x + threadIdx.x;
  if (i < n) p[i] = 0;
}

__global__ __launch_bounds__(256) void hist_k(const int* __restrict__ trg,
                                              int* __restrict__ counts, int m) {
  const int e = blockIdx.x * blockDim.x + threadIdx.x;
  if (e < m) atomicAdd(&counts[trg[e]], 1);
}

__global__ __launch_bounds__(256) void scanA_k(const int* __restrict__ counts,
                                               int* __restrict__ bsum, int n) {
  const int i = blockIdx.x * 256 + threadIdx.x;
  int v = (i < n) ? counts[i] : 0;
  v += __shfl_xor(v, 1);  v += __shfl_xor(v, 2);  v += __shfl_xor(v, 4);
  v += __shfl_xor(v, 8);  v += __shfl_xor(v, 16); v += __shfl_xor(v, 32);
  __shared__ int wsum[4];
  if ((threadIdx.x & 63) == 0) wsum[threadIdx.x >> 6] = v;
  __syncthreads();
  if (threadIdx.x == 0) bsum[blockIdx.x] = wsum[0] + wsum[1] + wsum[2] + wsum[3];
}

// PARALLEL exclusive scan of block sums (nblk <= 256)
__global__ __launch_bounds__(256) void scanB_k(int* __restrict__ bsum, int nblk,
                                               int* __restrict__ row_ptr, int n, int m) {
  const int i = threadIdx.x;
  const int lane = i & 63;
  const int wave = i >> 6;
  const int v = (i < nblk) ? bsum[i] : 0;
  int inc = v;
#pragma unroll
  for (int d = 1; d < 64; d <<= 1) {
    int t = __shfl_up(inc, d);
    if (lane >= d) inc += t;
  }
  __shared__ int wsum[4];
  if (lane == 63) wsum[wave] = inc;
  __syncthreads();
  int base = 0;
  for (int q = 0; q < wave; ++q) base += wsum[q];
  if (i < nblk) bsum[i] = base + inc - v;
  if (i == 0) row_ptr[n] = m;
}

__global__ __launch_bounds__(256) void scanC_k(const int* __restrict__ counts,
                                               const int* __restrict__ bsum,
                                               int* __restrict__ row_ptr,
                                               int* __restrict__ cursor, int n) {
  const int i = blockIdx.x * 256 + threadIdx.x;
  const int lane = threadIdx.x & 63;
  const int wave = threadIdx.x >> 6;
  const int v = (i < n) ? counts[i] : 0;
  int inc = v;
#pragma unroll
  for (int d = 1; d < 64; d <<= 1) {
    int t = __shfl_up(inc, d);
    if (lane >= d) inc += t;
  }
  __shared__ int wsum[4];
  if (lane == 63) wsum[wave] = inc;
  __syncthreads();
  int base = bsum[blockIdx.x];
  for (int q = 0; q < wave; ++q) base += wsum[q];
  const int excl = base + inc - v;
  if (i < n) { row_ptr[i] = excl; cursor[i] = excl; }
}

__global__ __launch_bounds__(256) void scatter_k(const int* __restrict__ src,
                                                 const int* __restrict__ trg,
                                                 int* __restrict__ cursor,
                                                 int* __restrict__ src_sorted, int m) {
  const int e = blockIdx.x * blockDim.x + threadIdx.x;
  if (e < m) {
    const int pos = atomicAdd(&cursor[trg[e]], 1);
    src_sorted[pos] = src[e];
  }
}

// ---------------------------------------------------------------------------
// One FULL routing layer (3 iterations fused), wave-per-node.
// CAPSULE-PER-LANE layout: lane = 8*slot + c; lane holds the FULL 8-dim
// capsule c (2 x float4, fp32) of edge slot -> 8 edges per wave-iteration.
// Capsule dot d and capsnorm are fully IN-LANE (no cross-lane ops); softmax
// denominator = 3 VALU DPP hops (xor1 0xB1, xor2 0x4E, xor7 row_half_mirror
// 0x141 -- together they span all 8 capsules). Slot-combine: xor8 via DPP
// row_ror:8 + 2 shfl. u in registers across iterations; first CAP edges
// cached in per-wave LDS at t=0; overflow re-gathered.
// MODE 1: dst = capsnorm(lrelu(u3))   (layer boundary)
// MODE 2: dst = lrelu(u3)             (final output)
// ---------------------------------------------------------------------------
template <int MODE>
__global__ __launch_bounds__(256) void rout_layer_k(
    const int* __restrict__ row_ptr, const int* __restrict__ src_sorted,
    const float* __restrict__ xn, float* __restrict__ dst, int n) {
  __shared__ float zc[4][CAP * 64];   // 16 KB: CAP edge rows per wave
  const int wv   = threadIdx.x >> 6;
  const int wid  = blockIdx.x * 4 + wv;
  const int lane = threadIdx.x & 63;
  if (wid >= n) return;
  const int g = lane >> 3;          // edge slot 0..7
  const int c = lane & 7;           // capsule (dims 8c..8c+7)
  const size_t rowj = (size_t)wid * 64 + c * 8;
  float* zbase = &zc[wv][0];

  // x-residual and initial u = capsule c of node row (8 fp32, in-lane)
  const float4 xa = *reinterpret_cast<const float4*>(xn + rowj);
  const float4 xbv = *reinterpret_cast<const float4*>(xn + rowj + 4);
  float u[8] = {xa.x, xa.y, xa.z, xa.w, xbv.x, xbv.y, xbv.z, xbv.w};

  const int e0  = row_ptr[wid];
  const int end = row_ptr[wid + 1];
  const int ntile = (end - e0 + 7) >> 3;

  for (int t = 0; t < 3; ++t) {
    float a[8] = {0.f, 0.f, 0.f, 0.f, 0.f, 0.f, 0.f, 0.f};

#define EDGE_BODY(ZA, ZB)                                              \
    {                                                                  \
      float d = (ZA).x * u[0];                                         \
      d = fmaf((ZA).y, u[1], d);                                       \
      d = fmaf((ZA).z, u[2], d);                                       \
      d = fmaf((ZA).w, u[3], d);                                       \
      d = fmaf((ZB).x, u[4], d);                                       \
      d = fmaf((ZB).y, u[5], d);                                       \
      d = fmaf((ZB).z, u[6], d);                                       \
      d = fmaf((ZB).w, u[7], d);       /* full capsule dot, in-lane */ \
      const float ee = __expf(d);      /* |d|<=1: unit capsules */     \
      float sm = dpp_add<0xB1>(ee);    /* xor1 */                      \
      sm = dpp_add<0x4E>(sm);          /* xor2 */                      \
      sm = dpp_add<0x141>(sm);         /* xor7: all 8 capsules */      \
      const float wgt = ee * __builtin_amdgcn_rcpf(sm);                \
      a[0] = fmaf((ZA).x, wgt, a[0]);                                  \
      a[1] = fmaf((ZA).y, wgt, a[1]);                                  \
      a[2] = fmaf((ZA).z, wgt, a[2]);                                  \
      a[3] = fmaf((ZA).w, wgt, a[3]);                                  \
      a[4] = fmaf((ZB).x, wgt, a[4]);                                  \
      a[5] = fmaf((ZB).y, wgt, a[5]);                                  \
      a[6] = fmaf((ZB).z, wgt, a[6]);                                  \
      a[7] = fmaf((ZB).w, wgt, a[7]);                                  \
    }

    if (t == 0) {
      int e = e0 + g;
      bool vn = e < end;
      int  sn = vn ? src_sorted[e] : wid;
      float4 zna = *reinterpret_cast<const float4*>(xn + (size_t)sn * 64 + c * 8);
      float4 znb = *reinterpret_cast<const float4*>(xn + (size_t)sn * 64 + c * 8 + 4);
      if (!vn) { zna = make_float4(0.f,0.f,0.f,0.f); znb = make_float4(0.f,0.f,0.f,0.f); }
      for (int it = 0; it < ntile; ++it) {
        const float4 za = zna, zb = znb;
        e += 8;
        const bool v2 = e < end;
        const int  s2 = v2 ? src_sorted[e] : wid;
        float4 ta = *reinterpret_cast<const float4*>(xn + (size_t)s2 * 64 + c * 8);
        float4 tb = *reinterpret_cast<const float4*>(xn + (size_t)s2 * 64 + c * 8 + 4);
        zna = v2 ? ta : make_float4(0.f,0.f,0.f,0.f);
        znb = v2 ? tb : make_float4(0.f,0.f,0.f,0.f);
        const int slot = it * 8 + g;
        if (slot < CAP) {
          *reinterpret_cast<float4*>(zbase + slot * 64 + c * 8)     = za;
          *reinterpret_cast<float4*>(zbase + slot * 64 + c * 8 + 4) = zb;
        }
        EDGE_BODY(za, zb)
      }
    } else {
      for (int it = 0; it < ntile; ++it) {
        const int slot = it * 8 + g;
        float4 za, zb;
        if (slot < CAP) {
          za = *reinterpret_cast<const float4*>(zbase + slot * 64 + c * 8);
          zb = *reinterpret_cast<const float4*>(zbase + slot * 64 + c * 8 + 4);
        } else {
          const int e = e0 + slot;
          const bool vv = e < end;
          const int ss = vv ? src_sorted[e] : wid;
          za = *reinterpret_cast<const float4*>(xn + (size_t)ss * 64 + c * 8);
          zb = *reinterpret_cast<const float4*>(xn + (size_t)ss * 64 + c * 8 + 4);
          if (!vv) { za = make_float4(0.f,0.f,0.f,0.f); zb = make_float4(0.f,0.f,0.f,0.f); }
        }
        EDGE_BODY(za, zb)
      }
    }
#undef EDGE_BODY

    // combine the 8 edge slots: lanes with same c across g (stride 8)
#pragma unroll
    for (int k = 0; k < 8; ++k) {
      a[k] = dpp_add<0x128>(a[k]);      // xor8 via row_ror:8 (VALU)
      a[k] += __shfl_xor(a[k], 16);
      a[k] += __shfl_xor(a[k], 32);
    }
    // + x, capsnorm (fully in-lane)
    a[0] += xa.x; a[1] += xa.y; a[2] += xa.z; a[3] += xa.w;
    a[4] += xbv.x; a[5] += xbv.y; a[6] += xbv.z; a[7] += xbv.w;
    float ss = a[0]*a[0];
#pragma unroll
    for (int k = 1; k < 8; ++k) ss = fmaf(a[k], a[k], ss);
    const float inv = 1.0f / fmaxf(sqrtf(ss), EPSN);
#pragma unroll
    for (int k = 0; k < 8; ++k) u[k] = a[k] * inv;
  }

  // boundary transforms (in-lane)
  float v[8];
#pragma unroll
  for (int k = 0; k < 8; ++k) {
    v[k] = u[k] > 0.f ? u[k] : SLOPE * u[k];
  }
  if (MODE == 1) {   // re-capsnorm for next layer's x
    float s3 = v[0]*v[0];
#pragma unroll
    for (int k = 1; k < 8; ++k) s3 = fmaf(v[k], v[k], s3);
    const float inv3 = 1.0f / fmaxf(sqrtf(s3), EPSN);
#pragma unroll
    for (int k = 0; k < 8; ++k) v[k] *= inv3;
  }
  if (g == 0) {
    *reinterpret_cast<float4*>(dst + rowj)     = make_float4(v[0], v[1], v[2], v[3]);
    *reinterpret_cast<float4*>(dst + rowj + 4) = make_float4(v[4], v[5], v[6], v[7]);
  }
}

// ---------------------------------------------------------------------------
extern "C" void kernel_launch(void* const* d_in, const int* in_sizes, int n_in,
                              void* d_out, int out_size, void* d_ws, size_t ws_size,
                              hipStream_t stream) {
  const float* x       = (const float*)d_in[0];
  const int*   src_trg = (const int*)d_in[1];
  const float* W       = (const float*)d_in[2];
  const float* b       = (const float*)d_in[3];

  const int hid    = in_sizes[3];          // 64
  const int in_dim = in_sizes[2] / hid;    // 500
  const int n      = in_sizes[0] / in_dim; // 50000
  const int m      = in_sizes[1] / 2;      // 500000
  const int* src = src_trg;
  const int* trg = src_trg + m;

  const size_t n64 = (size_t)n * hid;      // 3.2M floats
  float* xn_a = (float*)d_ws;              // layer-1 normalized features
  float* xn_b = xn_a + n64;                // layer-2 normalized features
  short* w2h  = (short*)(xn_b + n64);      // KPAD*64 bf16 hi (swizzled)
  short* w2l  = w2h + KPAD * 64;           // KPAD*64 bf16 lo
  float* zbuf = (float*)(w2l + KPAD * 64); // 16B zero granule (A-tail redirect)
  int*   ip   = (int*)(zbuf + 4);
  int* counts     = ip;                    // n
  int* row_ptr    = counts + n;            // n+1
  int* cursor     = row_ptr + n + 1;       // n
  int* bsum       = cursor + n;            // nblk
  const int nblk  = (n + 255) / 256;       // 196 (<= 256 required by scanB)
  int* src_sorted = bsum + nblk;           // m
  float* out = (float*)d_out;

  const int mg = (m + 255) / 256;

  // --- CSR build (once per call) ---
  zero_int_k<<<nblk, 256, 0, stream>>>(counts, n);
  hist_k<<<mg, 256, 0, stream>>>(trg, counts, m);
  scanA_k<<<nblk, 256, 0, stream>>>(counts, bsum, n);
  scanB_k<<<1, 256, 0, stream>>>(bsum, nblk, row_ptr, n, m);
  scanC_k<<<nblk, 256, 0, stream>>>(counts, bsum, row_ptr, cursor, n);
  scatter_k<<<mg, 256, 0, stream>>>(src, trg, cursor, src_sorted, m);

  // --- W prep + fused MFMA GEMM: xn_a = capsnorm(lrelu(x @ W + b)) ---
  prep_w_k<<<(KPAD * 64) / 256, 256, 0, stream>>>(W, w2h, w2l, zbuf, in_dim);
  gemm_mfma_capsnorm_k<<<(n + 63) / 64, 256, 0, stream>>>(
      x, w2h, w2l, b, zbuf, xn_a, n, in_dim);

  // --- routing: one fused kernel per layer (3 iterations each) ---
  const int rb = (n + 3) / 4;  // 4 waves (nodes) per 256-thread block
  rout_layer_k<1><<<rb, 256, 0, stream>>>(row_ptr, src_sorted, xn_a, xn_b, n);
  rout_layer_k<2><<<rb, 256, 0, stream>>>(row_ptr, src_sorted, xn_b, out, n);
}